// Round 2
// baseline (249.260 us; speedup 1.0000x reference)
//
#include <hip/hip_runtime.h>

#define DIM   384
#define HD    32
#define NH    12
#define NT    1024            // tokens per batch (32*32)
#define BATCH 8
#define SCALE 0.17677669529663687f

typedef short shortx8 __attribute__((ext_vector_type(8)));
typedef float floatx4 __attribute__((ext_vector_type(4)));

static __device__ __forceinline__ unsigned short f2bf(float f) {
    unsigned int u = __float_as_uint(f);
    u += 0x7fffu + ((u >> 16) & 1u);          // round-to-nearest-even
    return (unsigned short)(u >> 16);
}

// ---------------------------------------------------------------------------
// x (B, C, N) fp32 -> xt (B*N, C) bf16. 32x32 LDS tile transpose.
__global__ __launch_bounds__(256) void k_transpose(const float* __restrict__ x,
                                                   unsigned short* __restrict__ xt) {
    __shared__ float t[32][33];
    const int b  = blockIdx.z;
    const int c0 = blockIdx.y * 32;
    const int n0 = blockIdx.x * 32;
    const int tx = threadIdx.x;   // 0..31
    const int ty = threadIdx.y;   // 0..7
    const float* xb = x + (size_t)b * DIM * NT;
#pragma unroll
    for (int i = 0; i < 4; i++)
        t[ty + 8 * i][tx] = xb[(size_t)(c0 + ty + 8 * i) * NT + n0 + tx];
    __syncthreads();
    unsigned short* xtb = xt + (size_t)b * NT * DIM;
#pragma unroll
    for (int i = 0; i < 4; i++)
        xtb[(size_t)(n0 + ty + 8 * i) * DIM + c0 + tx] = f2bf(t[tx][ty + 8 * i]);
}

// ---------------------------------------------------------------------------
// Convert W_qkv (1152x384) and W_proj (384x384) fp32 -> bf16, one float4/thread.
#define NQ4 110592   // 442368/4
#define NP4 36864    // 147456/4
__global__ __launch_bounds__(256) void k_castw(const float* __restrict__ wq,
                                               const float* __restrict__ wp,
                                               unsigned short* __restrict__ wqb,
                                               unsigned short* __restrict__ wpb) {
    const int tid = blockIdx.x * 256 + threadIdx.x;   // 0..147455
    float4 v;
    unsigned short* dst;
    if (tid < NQ4) { v = ((const float4*)wq)[tid]; dst = wqb + (size_t)tid * 4; }
    else           { v = ((const float4*)wp)[tid - NQ4]; dst = wpb + (size_t)(tid - NQ4) * 4; }
    ushort4 p;
    p.x = f2bf(v.x); p.y = f2bf(v.y); p.z = f2bf(v.z); p.w = f2bf(v.w);
    *(ushort4*)dst = p;
}

// ---------------------------------------------------------------------------
// QKV GEMM: D[m][o] = sum_c xt[m][c] * Wqkv[o][c].  M=8192, N=1152, K=384.
// Block 256 thr = 4 waves; tile 64(M)x64(N); wave w -> rows [w*16, w*16+16).
// Scatter epilogue: q,k as (b,h,n,d); v transposed as vT (b,h,d,n).
__global__ __launch_bounds__(256) void k_qkv(const unsigned short* __restrict__ xt,
                                             const unsigned short* __restrict__ wqkv,
                                             unsigned short* __restrict__ qb,
                                             unsigned short* __restrict__ kb,
                                             unsigned short* __restrict__ vt) {
    const int lane = threadIdx.x & 63, w = threadIdx.x >> 6;
    const int quad = lane >> 4, l16 = lane & 15;
    const int m0 = blockIdx.x * 64 + w * 16;  // token base for this wave
    const int n0 = blockIdx.y * 64;           // output-feature base
    floatx4 acc[4] = {};
    const unsigned short* arow = xt + (size_t)(m0 + l16) * DIM + quad * 8;
    const unsigned short* brow = wqkv + (size_t)(n0 + l16) * DIM + quad * 8;
    for (int kt = 0; kt < DIM; kt += 32) {
        shortx8 a = *(const shortx8*)(arow + kt);
#pragma unroll
        for (int s = 0; s < 4; s++) {
            shortx8 bf = *(const shortx8*)(brow + (size_t)s * 16 * DIM + kt);
            acc[s] = __builtin_amdgcn_mfma_f32_16x16x32_bf16(a, bf, acc[s], 0, 0, 0);
        }
    }
#pragma unroll
    for (int s = 0; s < 4; s++) {
        const int o = n0 + s * 16 + l16;                 // 0..1151
        const int which = (o >= 2 * DIM) ? 2 : (o >= DIM ? 1 : 0); // wave-uniform
        const int rem = o - which * DIM;
        const int h = rem >> 5, d = rem & 31;
#pragma unroll
        for (int r = 0; r < 4; r++) {
            const int tok = m0 + quad * 4 + r;           // C/D: row = quad*4+reg
            const int bi = tok >> 10, n = tok & 1023;
            const unsigned short val = f2bf(acc[s][r]);
            const int hi = bi * NH + h;
            if (which == 0)      qb[((size_t)hi * NT + n) * HD + d] = val;
            else if (which == 1) kb[((size_t)hi * NT + n) * HD + d] = val;
            else                 vt[((size_t)hi * HD + d) * NT + n] = val;
        }
    }
}

// ---------------------------------------------------------------------------
// Flash attention: 1 wave per 16-row Q-tile; 32-key KV tiles; online softmax.
__global__ __launch_bounds__(256) void k_attn(const unsigned short* __restrict__ qb,
                                              const unsigned short* __restrict__ kb,
                                              const unsigned short* __restrict__ vt,
                                              unsigned short* __restrict__ aout) {
    __shared__ __align__(16) unsigned short plds[4][16 * 40];  // stride 40: 16B-aligned rows
    const int lane = threadIdx.x & 63, w = threadIdx.x >> 6;
    const int quad = lane >> 4, l16 = lane & 15;
    const int wid = blockIdx.x * 4 + w;      // 0..6143
    const int hi = wid >> 6;                 // head instance b*NH+h, 0..95
    const int qt = wid & 63;
    const int q0 = qt * 16;
    const unsigned short* Q = qb + (size_t)hi * NT * HD;
    const unsigned short* K = kb + (size_t)hi * NT * HD;
    const unsigned short* V = vt + (size_t)hi * HD * NT;

    const shortx8 qf = *(const shortx8*)(Q + (size_t)(q0 + l16) * HD + quad * 8);
    floatx4 o0 = {}, o1 = {};
    float mrow[4] = {-1e30f, -1e30f, -1e30f, -1e30f};
    float lrow[4] = {0.f, 0.f, 0.f, 0.f};
    const floatx4 zero = {};
    unsigned short* myp = &plds[w][0];

    for (int kt = 0; kt < NT; kt += 32) {
        shortx8 kf0 = *(const shortx8*)(K + (size_t)(kt + l16) * HD + quad * 8);
        shortx8 kf1 = *(const shortx8*)(K + (size_t)(kt + 16 + l16) * HD + quad * 8);
        floatx4 s0 = __builtin_amdgcn_mfma_f32_16x16x32_bf16(qf, kf0, zero, 0, 0, 0);
        floatx4 s1 = __builtin_amdgcn_mfma_f32_16x16x32_bf16(qf, kf1, zero, 0, 0, 0);
#pragma unroll
        for (int r = 0; r < 4; r++) {
            float a0 = s0[r] * SCALE, a1 = s1[r] * SCALE;
            float mx = fmaxf(a0, a1);
#pragma unroll
            for (int off = 1; off < 16; off <<= 1) mx = fmaxf(mx, __shfl_xor(mx, off));
            const float mnew = fmaxf(mrow[r], mx);
            const float alpha = __expf(mrow[r] - mnew);
            const float p0 = __expf(a0 - mnew), p1 = __expf(a1 - mnew);
            float rs = p0 + p1;
#pragma unroll
            for (int off = 1; off < 16; off <<= 1) rs += __shfl_xor(rs, off);
            lrow[r] = lrow[r] * alpha + rs;
            mrow[r] = mnew;
            o0[r] *= alpha; o1[r] *= alpha;
            const int row = quad * 4 + r;                 // C-layout row = query row
            myp[row * 40 + l16]      = f2bf(p0);          // col = key (0..15)
            myp[row * 40 + 16 + l16] = f2bf(p1);          // col = key (16..31)
        }
        __asm__ volatile("s_waitcnt lgkmcnt(0)" ::: "memory");
        // read P back in A-operand layout: m = l16, k = quad*8 + j
        shortx8 pf = *(const shortx8*)(myp + l16 * 40 + quad * 8);
        shortx8 v0 = *(const shortx8*)(V + (size_t)l16 * NT + kt + quad * 8);
        shortx8 v1 = *(const shortx8*)(V + (size_t)(16 + l16) * NT + kt + quad * 8);
        o0 = __builtin_amdgcn_mfma_f32_16x16x32_bf16(pf, v0, o0, 0, 0, 0);
        o1 = __builtin_amdgcn_mfma_f32_16x16x32_bf16(pf, v1, o1, 0, 0, 0);
        __asm__ volatile("" ::: "memory");  // keep next iter's LDS writes after this read
    }
    const int bi = hi / NH, h = hi % NH;
#pragma unroll
    for (int r = 0; r < 4; r++) {
        const int tok = q0 + quad * 4 + r;
        const float inv = 1.0f / lrow[r];
        const size_t rowbase = ((size_t)bi * NT + tok) * DIM + h * HD;
        aout[rowbase + l16]      = f2bf(o0[r] * inv);
        aout[rowbase + 16 + l16] = f2bf(o1[r] * inv);
    }
}

// ---------------------------------------------------------------------------
// Proj GEMM + fp32 bias, fp32 output in transposed (B, C, N) layout.
__global__ __launch_bounds__(256) void k_proj(const unsigned short* __restrict__ aout,
                                              const unsigned short* __restrict__ wproj,
                                              const float* __restrict__ bias,
                                              float* __restrict__ out) {
    const int lane = threadIdx.x & 63, w = threadIdx.x >> 6;
    const int quad = lane >> 4, l16 = lane & 15;
    const int m0 = blockIdx.x * 64 + w * 16;
    const int n0 = blockIdx.y * 64;
    floatx4 acc[4] = {};
    const unsigned short* arow = aout + (size_t)(m0 + l16) * DIM + quad * 8;
    const unsigned short* brow = wproj + (size_t)(n0 + l16) * DIM + quad * 8;
    for (int kt = 0; kt < DIM; kt += 32) {
        shortx8 a = *(const shortx8*)(arow + kt);
#pragma unroll
        for (int s = 0; s < 4; s++) {
            shortx8 bf = *(const shortx8*)(brow + (size_t)s * 16 * DIM + kt);
            acc[s] = __builtin_amdgcn_mfma_f32_16x16x32_bf16(a, bf, acc[s], 0, 0, 0);
        }
    }
    const int tokbase = m0 + quad * 4;            // 4 consecutive tokens (regs)
    const int bi = tokbase >> 10, nbase = tokbase & 1023;
#pragma unroll
    for (int s = 0; s < 4; s++) {
        const int o = n0 + s * 16 + l16;          // output channel
        const float bv = bias[o];
        float4 pack;
        pack.x = acc[s][0] + bv;
        pack.y = acc[s][1] + bv;
        pack.z = acc[s][2] + bv;
        pack.w = acc[s][3] + bv;
        *(float4*)(out + ((size_t)bi * DIM + o) * NT + nbase) = pack;
    }
}

// ---------------------------------------------------------------------------
extern "C" void kernel_launch(void* const* d_in, const int* in_sizes, int n_in,
                              void* d_out, int out_size, void* d_ws, size_t ws_size,
                              hipStream_t stream) {
    const float* x     = (const float*)d_in[0];
    const float* wqkv  = (const float*)d_in[1];
    const float* wproj = (const float*)d_in[2];
    const float* bias  = (const float*)d_in[3];
    float* out = (float*)d_out;

    // ws layout (bf16 elems): xt | q | k | vT | wqb | wpb ; aout reuses xt.
    unsigned short* xt   = (unsigned short*)d_ws;
    unsigned short* qb   = xt + 3145728;
    unsigned short* kb   = qb + 3145728;
    unsigned short* vt   = kb + 3145728;
    unsigned short* wqb  = vt + 3145728;
    unsigned short* wpb  = wqb + 442368;
    unsigned short* aout = xt;                    // xt dead after k_qkv

    k_transpose<<<dim3(32, 12, 8), dim3(32, 8), 0, stream>>>(x, xt);
    k_castw<<<576, 256, 0, stream>>>(wqkv, wproj, wqb, wpb);
    k_qkv<<<dim3(128, 18), 256, 0, stream>>>(xt, wqb, qb, kb, vt);
    k_attn<<<1536, 256, 0, stream>>>(qb, kb, vt, aout);
    k_proj<<<dim3(128, 6), 256, 0, stream>>>(aout, wpb, bias, out);
}

// Round 4
// 203.247 us; speedup vs baseline: 1.2264x; 1.2264x over previous
//
#include <hip/hip_runtime.h>

#define DIM   384
#define HD    32
#define NH    12
#define NT    1024            // tokens per batch (32*32)
#define BATCH 8
// p = exp2(s*C2 - M2)  ==  exp(s*SCALE - 8): fixed-max softmax, scale cancels in o/l
#define C2 0.2550347244197545f    // (1/sqrt(32)) * log2(e)
#define M2 11.541560327111707f    // 8 * log2(e)

typedef short shortx8 __attribute__((ext_vector_type(8)));
typedef float floatx4 __attribute__((ext_vector_type(4)));

static __device__ __forceinline__ unsigned short f2bf(float f) {
    unsigned int u = __float_as_uint(f);
    u += 0x7fffu + ((u >> 16) & 1u);          // round-to-nearest-even
    return (unsigned short)(u >> 16);
}

// ---------------------------------------------------------------------------
// x (B, C, N) fp32 -> xt (B*N, C) bf16. 32x32 LDS tile transpose.
__global__ __launch_bounds__(256) void k_transpose(const float* __restrict__ x,
                                                   unsigned short* __restrict__ xt) {
    __shared__ float t[32][33];
    const int b  = blockIdx.z;
    const int c0 = blockIdx.y * 32;
    const int n0 = blockIdx.x * 32;
    const int tx = threadIdx.x;   // 0..31
    const int ty = threadIdx.y;   // 0..7
    const float* xb = x + (size_t)b * DIM * NT;
#pragma unroll
    for (int i = 0; i < 4; i++)
        t[ty + 8 * i][tx] = xb[(size_t)(c0 + ty + 8 * i) * NT + n0 + tx];
    __syncthreads();
    unsigned short* xtb = xt + (size_t)b * NT * DIM;
#pragma unroll
    for (int i = 0; i < 4; i++)
        xtb[(size_t)(n0 + ty + 8 * i) * DIM + c0 + tx] = f2bf(t[tx][ty + 8 * i]);
}

// ---------------------------------------------------------------------------
// Convert W_qkv (1152x384) and W_proj (384x384) fp32 -> bf16, one float4/thread.
#define NQ4 110592   // 442368/4
__global__ __launch_bounds__(256) void k_castw(const float* __restrict__ wq,
                                               const float* __restrict__ wp,
                                               unsigned short* __restrict__ wqb,
                                               unsigned short* __restrict__ wpb) {
    const int tid = blockIdx.x * 256 + threadIdx.x;   // 0..147455
    float4 v;
    unsigned short* dst;
    if (tid < NQ4) { v = ((const float4*)wq)[tid]; dst = wqb + (size_t)tid * 4; }
    else           { v = ((const float4*)wp)[tid - NQ4]; dst = wpb + (size_t)(tid - NQ4) * 4; }
    ushort4 p;
    p.x = f2bf(v.x); p.y = f2bf(v.y); p.z = f2bf(v.z); p.w = f2bf(v.w);
    *(ushort4*)dst = p;
}

// ---------------------------------------------------------------------------
// QKV GEMM: D[m][o] = sum_c xt[m][c]*Wqkv[o][c]. M=8192,N=1152,K=384.
// 128x128 block tile, 4 waves, each wave 64x64 (4x4 MFMA accs).
// Scatter epilogue: q,k as (b,h,n,d); v transposed as vT (b,h,d,n).
__global__ __launch_bounds__(256) void k_qkv(const unsigned short* __restrict__ xt,
                                             const unsigned short* __restrict__ wqkv,
                                             unsigned short* __restrict__ qb,
                                             unsigned short* __restrict__ kb,
                                             unsigned short* __restrict__ vt) {
    const int lane = threadIdx.x & 63, w = threadIdx.x >> 6;
    const int quad = lane >> 4, l16 = lane & 15;
    const int m0 = blockIdx.x * 128 + (w & 1) * 64;
    const int n0 = blockIdx.y * 128 + (w >> 1) * 64;
    floatx4 acc[4][4] = {};
    const unsigned short* arow = xt + (size_t)(m0 + l16) * DIM + quad * 8;
    const unsigned short* brow = wqkv + (size_t)(n0 + l16) * DIM + quad * 8;
    for (int kt = 0; kt < DIM; kt += 32) {
        shortx8 a[4], b[4];
#pragma unroll
        for (int s = 0; s < 4; s++) a[s] = *(const shortx8*)(arow + (size_t)s * 16 * DIM + kt);
#pragma unroll
        for (int s = 0; s < 4; s++) b[s] = *(const shortx8*)(brow + (size_t)s * 16 * DIM + kt);
#pragma unroll
        for (int sm = 0; sm < 4; sm++)
#pragma unroll
            for (int sn = 0; sn < 4; sn++)
                acc[sm][sn] = __builtin_amdgcn_mfma_f32_16x16x32_bf16(a[sm], b[sn], acc[sm][sn], 0, 0, 0);
    }
    const int bi = m0 >> 10;                     // batch constant per block
#pragma unroll
    for (int sn = 0; sn < 4; sn++) {
        const int o = n0 + sn * 16 + l16;        // 0..1151
        const int which = (o >= 2 * DIM) ? 2 : (o >= DIM ? 1 : 0);  // wave-uniform
        const int rem = o - which * DIM;
        const int h = rem >> 5, d = rem & 31;
        const int hi = bi * NH + h;
#pragma unroll
        for (int sm = 0; sm < 4; sm++) {
#pragma unroll
            for (int r = 0; r < 4; r++) {
                const int n = (m0 + sm * 16 + quad * 4 + r) & 1023;
                const unsigned short val = f2bf(acc[sm][sn][r]);
                if (which == 0)      qb[((size_t)hi * NT + n) * HD + d] = val;
                else if (which == 1) kb[((size_t)hi * NT + n) * HD + d] = val;
                else                 vt[((size_t)hi * HD + d) * NT + n] = val;
            }
        }
    }
}

// ---------------------------------------------------------------------------
// Flash attention, LDS-free AND cross-lane-free. 1 wave per 16-query tile,
// 32-key steps. S^T via mfma(K,Q) with permuted K rows so exp'd scores land
// directly in the PV A-operand layout (m=query=l16, k=key=quad*8+j).
// Fixed-max softmax (M=8). Denominator via an extra MFMA against a ones
// vector: dsum[r] = sum_k P[q=quad*4+r][k] lands in the same C-layout rows
// as the O accumulator — no shuffles anywhere.
__global__ __launch_bounds__(256) void k_attn(const unsigned short* __restrict__ qb,
                                              const unsigned short* __restrict__ kb,
                                              const unsigned short* __restrict__ vt,
                                              unsigned short* __restrict__ aout) {
    const int lane = threadIdx.x & 63, w = threadIdx.x >> 6;
    const int quad = lane >> 4, l16 = lane & 15;
    const int wid = blockIdx.x * 4 + w;      // 0..6143
    const int hi = wid >> 6;                 // head instance b*NH+h
    const int q0 = (wid & 63) * 16;
    const unsigned short* Q = qb + (size_t)hi * NT * HD;
    const unsigned short* K = kb + (size_t)hi * NT * HD;
    const unsigned short* V = vt + (size_t)hi * HD * NT;

    const shortx8 qf = *(const shortx8*)(Q + (size_t)(q0 + l16) * HD + quad * 8);
    // permuted K-row index: A row m holds key (m>>2)*8 + (m&3)  (g0) / +4 (g1)
    const int krow = (l16 >> 2) * 8 + (l16 & 3);
    const shortx8 ones = {16256, 16256, 16256, 16256, 16256, 16256, 16256, 16256}; // bf16 1.0
    floatx4 olo = {}, ohi = {}, dsum = {};
    const floatx4 zero = {};

    for (int kt = 0; kt < NT; kt += 32) {
        const shortx8 kf0 = *(const shortx8*)(K + (size_t)(kt + krow) * HD + quad * 8);
        const shortx8 kf1 = *(const shortx8*)(K + (size_t)(kt + krow + 4) * HD + quad * 8);
        const shortx8 vlo = *(const shortx8*)(V + (size_t)l16 * NT + kt + quad * 8);
        const shortx8 vhi = *(const shortx8*)(V + (size_t)(16 + l16) * NT + kt + quad * 8);
        const floatx4 st0 = __builtin_amdgcn_mfma_f32_16x16x32_bf16(kf0, qf, zero, 0, 0, 0);
        const floatx4 st1 = __builtin_amdgcn_mfma_f32_16x16x32_bf16(kf1, qf, zero, 0, 0, 0);
        shortx8 pf;
#pragma unroll
        for (int r = 0; r < 4; r++)
            pf[r] = (short)f2bf(__builtin_amdgcn_exp2f(fmaf(st0[r], C2, -M2)));
#pragma unroll
        for (int r = 0; r < 4; r++)
            pf[4 + r] = (short)f2bf(__builtin_amdgcn_exp2f(fmaf(st1[r], C2, -M2)));
        olo  = __builtin_amdgcn_mfma_f32_16x16x32_bf16(pf, vlo, olo, 0, 0, 0);
        ohi  = __builtin_amdgcn_mfma_f32_16x16x32_bf16(pf, vhi, ohi, 0, 0, 0);
        dsum = __builtin_amdgcn_mfma_f32_16x16x32_bf16(pf, ones, dsum, 0, 0, 0);
    }
    const int bi = hi / NH, h = hi % NH;
#pragma unroll
    for (int r = 0; r < 4; r++) {
        const float inv = 1.0f / dsum[r];         // denom for query quad*4+r
        const int tok = q0 + quad * 4 + r;
        const size_t base = ((size_t)bi * NT + tok) * DIM + h * HD;
        aout[base + l16]      = f2bf(olo[r] * inv);
        aout[base + 16 + l16] = f2bf(ohi[r] * inv);
    }
}

// ---------------------------------------------------------------------------
// Proj GEMM + fp32 bias, fp32 output in transposed (B, C, N) layout.
// 128x128 block tile, 4 waves x (64x64).
__global__ __launch_bounds__(256) void k_proj(const unsigned short* __restrict__ aout,
                                              const unsigned short* __restrict__ wproj,
                                              const float* __restrict__ bias,
                                              float* __restrict__ out) {
    const int lane = threadIdx.x & 63, w = threadIdx.x >> 6;
    const int quad = lane >> 4, l16 = lane & 15;
    const int m0 = blockIdx.x * 128 + (w & 1) * 64;
    const int n0 = blockIdx.y * 128 + (w >> 1) * 64;
    floatx4 acc[4][4] = {};
    const unsigned short* arow = aout + (size_t)(m0 + l16) * DIM + quad * 8;
    const unsigned short* brow = wproj + (size_t)(n0 + l16) * DIM + quad * 8;
    for (int kt = 0; kt < DIM; kt += 32) {
        shortx8 a[4], b[4];
#pragma unroll
        for (int s = 0; s < 4; s++) a[s] = *(const shortx8*)(arow + (size_t)s * 16 * DIM + kt);
#pragma unroll
        for (int s = 0; s < 4; s++) b[s] = *(const shortx8*)(brow + (size_t)s * 16 * DIM + kt);
#pragma unroll
        for (int sm = 0; sm < 4; sm++)
#pragma unroll
            for (int sn = 0; sn < 4; sn++)
                acc[sm][sn] = __builtin_amdgcn_mfma_f32_16x16x32_bf16(a[sm], b[sn], acc[sm][sn], 0, 0, 0);
    }
    const int bi = m0 >> 10;
#pragma unroll
    for (int sn = 0; sn < 4; sn++) {
        const int o = n0 + sn * 16 + l16;
        const float bv = bias[o];
        float* orow = out + ((size_t)bi * DIM + o) * NT;
#pragma unroll
        for (int sm = 0; sm < 4; sm++) {
            const int nb = (m0 + sm * 16 + quad * 4) & 1023;
            float4 pack;
            pack.x = acc[sm][sn][0] + bv;
            pack.y = acc[sm][sn][1] + bv;
            pack.z = acc[sm][sn][2] + bv;
            pack.w = acc[sm][sn][3] + bv;
            *(float4*)(orow + nb) = pack;
        }
    }
}

// ---------------------------------------------------------------------------
extern "C" void kernel_launch(void* const* d_in, const int* in_sizes, int n_in,
                              void* d_out, int out_size, void* d_ws, size_t ws_size,
                              hipStream_t stream) {
    const float* x     = (const float*)d_in[0];
    const float* wqkv  = (const float*)d_in[1];
    const float* wproj = (const float*)d_in[2];
    const float* bias  = (const float*)d_in[3];
    float* out = (float*)d_out;

    // ws layout (bf16 elems): xt | q | k | vT | wqb | wpb ; aout reuses xt.
    unsigned short* xt   = (unsigned short*)d_ws;
    unsigned short* qb   = xt + 3145728;
    unsigned short* kb   = qb + 3145728;
    unsigned short* vt   = kb + 3145728;
    unsigned short* wqb  = vt + 3145728;
    unsigned short* wpb  = wqb + 442368;
    unsigned short* aout = xt;                    // xt dead after k_qkv

    k_transpose<<<dim3(32, 12, 8), dim3(32, 8), 0, stream>>>(x, xt);
    k_castw<<<576, 256, 0, stream>>>(wqkv, wproj, wqb, wpb);
    k_qkv<<<dim3(64, 9), 256, 0, stream>>>(xt, wqb, qb, kb, vt);
    k_attn<<<1536, 256, 0, stream>>>(qb, kb, vt, aout);
    k_proj<<<dim3(64, 3), 256, 0, stream>>>(aout, wpb, bias, out);
}

// Round 5
// 149.700 us; speedup vs baseline: 1.6651x; 1.3577x over previous
//
#include <hip/hip_runtime.h>

#define DIM   384
#define HD    32
#define NH    12
#define NT    1024            // tokens per batch (32*32)
#define BATCH 8
// p = exp2(s*C2 - M2)  ==  exp(s*SCALE - 8): fixed-max softmax, scale cancels in o/l
#define C2 0.2550347244197545f    // (1/sqrt(32)) * log2(e)
#define M2 11.541560327111707f    // 8 * log2(e)

// Fragment-order layout for a k-major matrix X[row][k], K=384 (12 ksteps):
//   elem addr = ((tile16*12 + kstep)*4 + kgroup)*128 + (row&15)*8 + (k&7)
// A wave's 16x32 fragment load = 64 lanes x 16B = 1KB contiguous.

typedef short shortx8 __attribute__((ext_vector_type(8)));
typedef float floatx4 __attribute__((ext_vector_type(4)));

static __device__ __forceinline__ unsigned short f2bf(float f) {
    unsigned int u = __float_as_uint(f);
    u += 0x7fffu + ((u >> 16) & 1u);          // round-to-nearest-even
    return (unsigned short)(u >> 16);
}

// ---------------------------------------------------------------------------
// x (B, C, N) fp32 -> xtf: bf16 A-fragment order (token-major tiles, k=channel).
__global__ __launch_bounds__(256) void k_transpose(const float* __restrict__ x,
                                                   unsigned short* __restrict__ xtf) {
    __shared__ float t[32][33];
    const int b = blockIdx.z, kstep = blockIdx.y, n0 = blockIdx.x * 32;
    const int tid = threadIdx.x;
    const int tx = tid & 31, ty = tid >> 5;          // load indexing
    const float* xb = x + ((size_t)b * DIM + kstep * 32) * NT + n0;
#pragma unroll
    for (int i = 0; i < 4; i++)
        t[ty + 8 * i][tx] = xb[(size_t)(ty + 8 * i) * NT + tx];
    __syncthreads();
    // write 8B per thread in fragment order
    const int mtl = tid >> 7, kq = (tid >> 5) & 3, rem = tid & 31;
    const int mrow = rem >> 1, krH = rem & 1;
    ushort4 p;
    p.x = f2bf(t[kq * 8 + krH * 4 + 0][mtl * 16 + mrow]);
    p.y = f2bf(t[kq * 8 + krH * 4 + 1][mtl * 16 + mrow]);
    p.z = f2bf(t[kq * 8 + krH * 4 + 2][mtl * 16 + mrow]);
    p.w = f2bf(t[kq * 8 + krH * 4 + 3][mtl * 16 + mrow]);
    const size_t mtile = ((size_t)b * 1024 + n0) / 16 + mtl;
    const size_t off = ((mtile * 12 + kstep) * 4 + kq) * 128 + mrow * 8 + krH * 4;
    *(ushort4*)(xtf + off) = p;
}

// ---------------------------------------------------------------------------
// W_qkv (1152x384) and W_proj (384x384) fp32 -> bf16 B-fragment order.
#define NCQ 110592   // 442368/4 chunks of 4 elems
__global__ __launch_bounds__(256) void k_castw(const float* __restrict__ wq,
                                               const float* __restrict__ wp,
                                               unsigned short* __restrict__ wqf,
                                               unsigned short* __restrict__ wpf) {
    const int tid = blockIdx.x * 256 + threadIdx.x;   // 0..147455
    const float* src; unsigned short* dst; int ci;
    if (tid < NCQ) { ci = tid; src = wq; dst = wqf; }
    else           { ci = tid - NCQ; src = wp; dst = wpf; }
    const int krH = ci & 1, orow = (ci >> 1) & 15, quad = (ci >> 5) & 3;
    const int t2 = ci >> 7, kstep = t2 % 12, ntile = t2 / 12;
    const int row = ntile * 16 + orow, col = kstep * 32 + quad * 8 + krH * 4;
    const float4 v = *(const float4*)(src + (size_t)row * DIM + col);
    ushort4 p;
    p.x = f2bf(v.x); p.y = f2bf(v.y); p.z = f2bf(v.z); p.w = f2bf(v.w);
    *(ushort4*)(dst + (size_t)ci * 4) = p;
}

// ---------------------------------------------------------------------------
// QKV GEMM from fragment-ordered operands. 128x128 block, 4 waves x 64x64.
// Scatter epilogue: q,k as (b,h,n,d); v transposed as vT (b,h,d,n).
__global__ __launch_bounds__(256) void k_qkv(const unsigned short* __restrict__ xtf,
                                             const unsigned short* __restrict__ wqf,
                                             unsigned short* __restrict__ qb,
                                             unsigned short* __restrict__ kb,
                                             unsigned short* __restrict__ vt) {
    const int lane = threadIdx.x & 63, w = threadIdx.x >> 6;
    const int quad = lane >> 4, l16 = lane & 15;
    const int m0 = blockIdx.x * 128 + (w & 1) * 64;
    const int n0 = blockIdx.y * 128 + (w >> 1) * 64;
    floatx4 acc[4][4] = {};
    const unsigned short* abase = xtf + ((size_t)(m0 >> 4) * 12 * 4 + quad) * 128 + l16 * 8;
    const unsigned short* bbase = wqf + ((size_t)(n0 >> 4) * 12 * 4 + quad) * 128 + l16 * 8;
    for (int ks = 0; ks < 12; ks++) {
        shortx8 a[4], b[4];
#pragma unroll
        for (int s = 0; s < 4; s++) a[s] = *(const shortx8*)(abase + s * 6144 + ks * 512);
#pragma unroll
        for (int s = 0; s < 4; s++) b[s] = *(const shortx8*)(bbase + s * 6144 + ks * 512);
#pragma unroll
        for (int sm = 0; sm < 4; sm++)
#pragma unroll
            for (int sn = 0; sn < 4; sn++)
                acc[sm][sn] = __builtin_amdgcn_mfma_f32_16x16x32_bf16(a[sm], b[sn], acc[sm][sn], 0, 0, 0);
    }
    const int bi = m0 >> 10;                     // batch constant per block
#pragma unroll
    for (int sn = 0; sn < 4; sn++) {
        const int o = n0 + sn * 16 + l16;        // 0..1151
        const int which = (o >= 2 * DIM) ? 2 : (o >= DIM ? 1 : 0);  // wave-uniform
        const int rem = o - which * DIM;
        const int h = rem >> 5, d = rem & 31;
        const int hi = bi * NH + h;
#pragma unroll
        for (int sm = 0; sm < 4; sm++) {
#pragma unroll
            for (int r = 0; r < 4; r++) {
                const int n = (m0 + sm * 16 + quad * 4 + r) & 1023;
                const unsigned short val = f2bf(acc[sm][sn][r]);
                if (which == 0)      qb[((size_t)hi * NT + n) * HD + d] = val;
                else if (which == 1) kb[((size_t)hi * NT + n) * HD + d] = val;
                else                 vt[((size_t)hi * HD + d) * NT + n] = val;
            }
        }
    }
}

// ---------------------------------------------------------------------------
// Flash attention, LDS/cross-lane free. 1 wave per 32 queries (2 Q-tiles share
// every K/V load; 2 independent MFMA->exp->MFMA chains). Fixed-max softmax,
// denominator via ones-MFMA. Epilogue writes A-fragment order for k_proj.
// Block swizzle: all 8 blocks of one head share blockIdx%8 (one XCD's L2).
__global__ __launch_bounds__(256) void k_attn(const unsigned short* __restrict__ qb,
                                              const unsigned short* __restrict__ kb,
                                              const unsigned short* __restrict__ vt,
                                              unsigned short* __restrict__ aoutf) {
    const int lane = threadIdx.x & 63, w = threadIdx.x >> 6;
    const int quad = lane >> 4, l16 = lane & 15;
    const int g = blockIdx.x & 7, j = blockIdx.x >> 3;   // 768 blocks
    const int hi = g * 12 + j % 12;                      // head instance b*NH+h
    const int q0 = ((j / 12) * 4 + w) * 32;              // 32 queries per wave
    const unsigned short* Q = qb + (size_t)hi * NT * HD;
    const unsigned short* K = kb + (size_t)hi * NT * HD;
    const unsigned short* V = vt + (size_t)hi * HD * NT;

    const shortx8 qfA = *(const shortx8*)(Q + (size_t)(q0 + l16) * HD + quad * 8);
    const shortx8 qfB = *(const shortx8*)(Q + (size_t)(q0 + 16 + l16) * HD + quad * 8);
    // permuted K-row index: A row m holds key (m>>2)*8 + (m&3)  (g0) / +4 (g1)
    const int krow = (l16 >> 2) * 8 + (l16 & 3);
    const shortx8 ones = {16256, 16256, 16256, 16256, 16256, 16256, 16256, 16256}; // bf16 1.0
    floatx4 oloA = {}, ohiA = {}, dsA = {};
    floatx4 oloB = {}, ohiB = {}, dsB = {};
    const floatx4 zero = {};

    for (int kt = 0; kt < NT; kt += 32) {
        const shortx8 kf0 = *(const shortx8*)(K + (size_t)(kt + krow) * HD + quad * 8);
        const shortx8 kf1 = *(const shortx8*)(K + (size_t)(kt + krow + 4) * HD + quad * 8);
        const shortx8 vlo = *(const shortx8*)(V + (size_t)l16 * NT + kt + quad * 8);
        const shortx8 vhi = *(const shortx8*)(V + (size_t)(16 + l16) * NT + kt + quad * 8);
        const floatx4 sA0 = __builtin_amdgcn_mfma_f32_16x16x32_bf16(kf0, qfA, zero, 0, 0, 0);
        const floatx4 sA1 = __builtin_amdgcn_mfma_f32_16x16x32_bf16(kf1, qfA, zero, 0, 0, 0);
        const floatx4 sB0 = __builtin_amdgcn_mfma_f32_16x16x32_bf16(kf0, qfB, zero, 0, 0, 0);
        const floatx4 sB1 = __builtin_amdgcn_mfma_f32_16x16x32_bf16(kf1, qfB, zero, 0, 0, 0);
        shortx8 pfA, pfB;
#pragma unroll
        for (int r = 0; r < 4; r++) {
            pfA[r]     = (short)f2bf(__builtin_amdgcn_exp2f(fmaf(sA0[r], C2, -M2)));
            pfA[4 + r] = (short)f2bf(__builtin_amdgcn_exp2f(fmaf(sA1[r], C2, -M2)));
            pfB[r]     = (short)f2bf(__builtin_amdgcn_exp2f(fmaf(sB0[r], C2, -M2)));
            pfB[4 + r] = (short)f2bf(__builtin_amdgcn_exp2f(fmaf(sB1[r], C2, -M2)));
        }
        oloA = __builtin_amdgcn_mfma_f32_16x16x32_bf16(pfA, vlo, oloA, 0, 0, 0);
        ohiA = __builtin_amdgcn_mfma_f32_16x16x32_bf16(pfA, vhi, ohiA, 0, 0, 0);
        dsA  = __builtin_amdgcn_mfma_f32_16x16x32_bf16(pfA, ones, dsA, 0, 0, 0);
        oloB = __builtin_amdgcn_mfma_f32_16x16x32_bf16(pfB, vlo, oloB, 0, 0, 0);
        ohiB = __builtin_amdgcn_mfma_f32_16x16x32_bf16(pfB, vhi, ohiB, 0, 0, 0);
        dsB  = __builtin_amdgcn_mfma_f32_16x16x32_bf16(pfB, ones, dsB, 0, 0, 0);
    }
    // epilogue: write in A-fragment order (k = channel = h*32 + col)
    const int bi = hi / NH, h = hi % NH;
    const size_t mt0 = (size_t)bi * 64 + (q0 >> 4);      // mtile of tile A
    const int kqlo = l16 >> 3, kr = l16 & 7;
    unsigned short* pA = aoutf + (mt0 * 12 + h) * 512 + kr;
    unsigned short* pB = aoutf + ((mt0 + 1) * 12 + h) * 512 + kr;
#pragma unroll
    for (int r = 0; r < 4; r++) {
        const int mrow8 = (quad * 4 + r) * 8;
        const float invA = 1.0f / dsA[r], invB = 1.0f / dsB[r];
        pA[kqlo * 128 + mrow8]       = f2bf(oloA[r] * invA);
        pA[(2 + kqlo) * 128 + mrow8] = f2bf(ohiA[r] * invA);
        pB[kqlo * 128 + mrow8]       = f2bf(oloB[r] * invB);
        pB[(2 + kqlo) * 128 + mrow8] = f2bf(ohiB[r] * invB);
    }
}

// ---------------------------------------------------------------------------
// Proj GEMM from fragment-ordered operands + fp32 bias, fp32 (B, C, N) output.
__global__ __launch_bounds__(256) void k_proj(const unsigned short* __restrict__ aoutf,
                                              const unsigned short* __restrict__ wpf,
                                              const float* __restrict__ bias,
                                              float* __restrict__ out) {
    const int lane = threadIdx.x & 63, w = threadIdx.x >> 6;
    const int quad = lane >> 4, l16 = lane & 15;
    const int m0 = blockIdx.x * 128 + (w & 1) * 64;
    const int n0 = blockIdx.y * 128 + (w >> 1) * 64;
    floatx4 acc[4][4] = {};
    const unsigned short* abase = aoutf + ((size_t)(m0 >> 4) * 12 * 4 + quad) * 128 + l16 * 8;
    const unsigned short* bbase = wpf + ((size_t)(n0 >> 4) * 12 * 4 + quad) * 128 + l16 * 8;
    for (int ks = 0; ks < 12; ks++) {
        shortx8 a[4], b[4];
#pragma unroll
        for (int s = 0; s < 4; s++) a[s] = *(const shortx8*)(abase + s * 6144 + ks * 512);
#pragma unroll
        for (int s = 0; s < 4; s++) b[s] = *(const shortx8*)(bbase + s * 6144 + ks * 512);
#pragma unroll
        for (int sm = 0; sm < 4; sm++)
#pragma unroll
            for (int sn = 0; sn < 4; sn++)
                acc[sm][sn] = __builtin_amdgcn_mfma_f32_16x16x32_bf16(a[sm], b[sn], acc[sm][sn], 0, 0, 0);
    }
    const int bi = m0 >> 10;
#pragma unroll
    for (int sn = 0; sn < 4; sn++) {
        const int o = n0 + sn * 16 + l16;
        const float bv = bias[o];
        float* orow = out + ((size_t)bi * DIM + o) * NT;
#pragma unroll
        for (int sm = 0; sm < 4; sm++) {
            const int nb = (m0 + sm * 16 + quad * 4) & 1023;
            float4 pack;
            pack.x = acc[sm][sn][0] + bv;
            pack.y = acc[sm][sn][1] + bv;
            pack.z = acc[sm][sn][2] + bv;
            pack.w = acc[sm][sn][3] + bv;
            *(float4*)(orow + nb) = pack;
        }
    }
}

// ---------------------------------------------------------------------------
extern "C" void kernel_launch(void* const* d_in, const int* in_sizes, int n_in,
                              void* d_out, int out_size, void* d_ws, size_t ws_size,
                              hipStream_t stream) {
    const float* x     = (const float*)d_in[0];
    const float* wqkv  = (const float*)d_in[1];
    const float* wproj = (const float*)d_in[2];
    const float* bias  = (const float*)d_in[3];
    float* out = (float*)d_out;

    // ws layout (bf16 elems): xtf | q | k | vT | wqf | wpf ; aoutf reuses xtf.
    unsigned short* xtf  = (unsigned short*)d_ws;
    unsigned short* qb   = xtf + 3145728;
    unsigned short* kb   = qb + 3145728;
    unsigned short* vt   = kb + 3145728;
    unsigned short* wqf  = vt + 3145728;
    unsigned short* wpf  = wqf + 442368;
    unsigned short* aoutf = xtf;                  // xtf dead after k_qkv

    k_transpose<<<dim3(32, 12, 8), 256, 0, stream>>>(x, xtf);
    k_castw<<<576, 256, 0, stream>>>(wqkv, wproj, wqf, wpf);
    k_qkv<<<dim3(64, 9), 256, 0, stream>>>(xtf, wqf, qb, kb, vt);
    k_attn<<<768, 256, 0, stream>>>(qb, kb, vt, aoutf);
    k_proj<<<dim3(64, 3), 256, 0, stream>>>(aoutf, wpf, bias, out);
}

// Round 6
// 128.640 us; speedup vs baseline: 1.9377x; 1.1637x over previous
//
#include <hip/hip_runtime.h>
#include <hip/hip_bf16.h>

#define DIM   384
#define HD    32
#define NH    12
#define NT    1024            // tokens per batch (32*32)
#define BATCH 8
// p = exp2(s*C2 - M2)  ==  exp(s*SCALE - 8): fixed-max softmax, scale cancels in o/l
#define C2 0.2550347244197545f    // (1/sqrt(32)) * log2(e)
#define M2 11.541560327111707f    // 8 * log2(e)

// Fragment-order layout for a k-major matrix X[row][k], K=384 (12 ksteps):
//   elem addr = ((tile16*12 + kstep)*4 + kgroup)*128 + (row&15)*8 + (k&7)
// A wave's 16x32 fragment load = 64 lanes x 16B = 1KB contiguous.

typedef short shortx8 __attribute__((ext_vector_type(8)));
typedef float floatx4 __attribute__((ext_vector_type(4)));

#define GLD_LDS(gp, lp) \
    __builtin_amdgcn_global_load_lds((__attribute__((address_space(1))) const void*)(gp), \
                                     (__attribute__((address_space(3))) void*)(lp), 16, 0, 0)

static __device__ __forceinline__ unsigned short f2bf(float f) {
    unsigned int u = __float_as_uint(f);
    u += 0x7fffu + ((u >> 16) & 1u);          // round-to-nearest-even
    return (unsigned short)(u >> 16);
}

// ---------------------------------------------------------------------------
// Fused pre-pass. Blocks [0,3072): x (B,C,N) fp32 -> xtf bf16 A-fragment order.
// Blocks [3072,3648): W_qkv/W_proj fp32 -> bf16 B-fragment order.
__global__ __launch_bounds__(256) void k_pre(const float* __restrict__ x,
                                             const float* __restrict__ wq,
                                             const float* __restrict__ wp,
                                             unsigned short* __restrict__ xtf,
                                             unsigned short* __restrict__ wqf,
                                             unsigned short* __restrict__ wpf) {
    const int bid = blockIdx.x;
    if (bid < 3072) {
        __shared__ float t[32][33];
        const int xb_ = bid & 31, kstep = (bid >> 5) % 12, b = bid / 384;
        const int n0 = xb_ * 32;
        const int tid = threadIdx.x;
        const int tx = tid & 31, ty = tid >> 5;
        const float* xb = x + ((size_t)b * DIM + kstep * 32) * NT + n0;
#pragma unroll
        for (int i = 0; i < 4; i++)
            t[ty + 8 * i][tx] = xb[(size_t)(ty + 8 * i) * NT + tx];
        __syncthreads();
        const int mtl = tid >> 7, kq = (tid >> 5) & 3, rem = tid & 31;
        const int mrow = rem >> 1, krH = rem & 1;
        ushort4 p;
        p.x = f2bf(t[kq * 8 + krH * 4 + 0][mtl * 16 + mrow]);
        p.y = f2bf(t[kq * 8 + krH * 4 + 1][mtl * 16 + mrow]);
        p.z = f2bf(t[kq * 8 + krH * 4 + 2][mtl * 16 + mrow]);
        p.w = f2bf(t[kq * 8 + krH * 4 + 3][mtl * 16 + mrow]);
        const size_t mtile = ((size_t)b * 1024 + n0) / 16 + mtl;
        const size_t off = ((mtile * 12 + kstep) * 4 + kq) * 128 + mrow * 8 + krH * 4;
        *(ushort4*)(xtf + off) = p;
    } else {
        const int tid = (bid - 3072) * 256 + threadIdx.x;   // 0..147455
        const float* src; unsigned short* dst; int ci;
        if (tid < 110592) { ci = tid; src = wq; dst = wqf; }
        else              { ci = tid - 110592; src = wp; dst = wpf; }
        const int krH = ci & 1, orow = (ci >> 1) & 15, quad = (ci >> 5) & 3;
        const int t2 = ci >> 7, kstep = t2 % 12, ntile = t2 / 12;
        const int row = ntile * 16 + orow, col = kstep * 32 + quad * 8 + krH * 4;
        const float4 v = *(const float4*)(src + (size_t)row * DIM + col);
        ushort4 p;
        p.x = f2bf(v.x); p.y = f2bf(v.y); p.z = f2bf(v.z); p.w = f2bf(v.w);
        *(ushort4*)(dst + (size_t)ci * 4) = p;
    }
}

// ---------------------------------------------------------------------------
// QKV GEMM from fragment-ordered operands. 128x128 block, 4 waves x 64x64,
// register-prefetch software pipeline over the 12 ksteps.
// Scatter epilogue: q,k as (b,h,n,d); v transposed as vT (b,h,d,n).
__global__ __launch_bounds__(256) void k_qkv(const unsigned short* __restrict__ xtf,
                                             const unsigned short* __restrict__ wqf,
                                             unsigned short* __restrict__ qb,
                                             unsigned short* __restrict__ kb,
                                             unsigned short* __restrict__ vt) {
    const int lane = threadIdx.x & 63, w = threadIdx.x >> 6;
    const int quad = lane >> 4, l16 = lane & 15;
    const int m0 = blockIdx.x * 128 + (w & 1) * 64;
    const int n0 = blockIdx.y * 128 + (w >> 1) * 64;
    floatx4 acc[4][4] = {};
    const unsigned short* abase = xtf + ((size_t)(m0 >> 4) * 12 * 4 + quad) * 128 + l16 * 8;
    const unsigned short* bbase = wqf + ((size_t)(n0 >> 4) * 12 * 4 + quad) * 128 + l16 * 8;
    shortx8 a[4], b[4], a2[4], b2[4];
#pragma unroll
    for (int s = 0; s < 4; s++) {
        a[s] = *(const shortx8*)(abase + s * 6144);
        b[s] = *(const shortx8*)(bbase + s * 6144);
    }
    for (int ks = 0; ks < 12; ks++) {
        if (ks < 11) {
#pragma unroll
            for (int s = 0; s < 4; s++) {
                a2[s] = *(const shortx8*)(abase + s * 6144 + (ks + 1) * 512);
                b2[s] = *(const shortx8*)(bbase + s * 6144 + (ks + 1) * 512);
            }
        }
#pragma unroll
        for (int sm = 0; sm < 4; sm++)
#pragma unroll
            for (int sn = 0; sn < 4; sn++)
                acc[sm][sn] = __builtin_amdgcn_mfma_f32_16x16x32_bf16(a[sm], b[sn], acc[sm][sn], 0, 0, 0);
#pragma unroll
        for (int s = 0; s < 4; s++) { a[s] = a2[s]; b[s] = b2[s]; }
    }
    const int bi = m0 >> 10;                     // batch constant per block
#pragma unroll
    for (int sn = 0; sn < 4; sn++) {
        const int o = n0 + sn * 16 + l16;        // 0..1151
        const int which = (o >= 2 * DIM) ? 2 : (o >= DIM ? 1 : 0);  // wave-uniform
        const int rem = o - which * DIM;
        const int h = rem >> 5, d = rem & 31;
        const int hi = bi * NH + h;
#pragma unroll
        for (int sm = 0; sm < 4; sm++) {
#pragma unroll
            for (int r = 0; r < 4; r++) {
                const int n = (m0 + sm * 16 + quad * 4 + r) & 1023;
                const unsigned short val = f2bf(acc[sm][sn][r]);
                if (which == 0)      qb[((size_t)hi * NT + n) * HD + d] = val;
                else if (which == 1) kb[((size_t)hi * NT + n) * HD + d] = val;
                else                 vt[((size_t)hi * HD + d) * NT + n] = val;
            }
        }
    }
}

// ---------------------------------------------------------------------------
// Flash attention. 4 waves/block share one head; per 32-key tile the 4 K/V
// MFMA fragments (4x1KB, lane-determined and wave-independent) are staged
// once into LDS (each wave gathers one fragment via global_load_lds, 16B/lane)
// and read back conflict-free at lane*16. Double-buffered; __syncthreads
// drains vmcnt+lgkm. 2 Q-tiles (32 queries) per wave; fixed-max softmax;
// denominator via ones-MFMA. Epilogue writes A-fragment order for k_proj.
__global__ __launch_bounds__(256) void k_attn(const unsigned short* __restrict__ qb,
                                              const unsigned short* __restrict__ kb,
                                              const unsigned short* __restrict__ vt,
                                              unsigned short* __restrict__ aoutf) {
    __shared__ __align__(16) unsigned short frag[2][4][512];   // [buf][frag][elems]
    const int lane = threadIdx.x & 63, w = threadIdx.x >> 6;
    const int quad = lane >> 4, l16 = lane & 15;
    const int g = blockIdx.x & 7, j = blockIdx.x >> 3;   // 768 blocks
    const int hi = g * 12 + j % 12;                      // head instance b*NH+h
    const int q0 = ((j / 12) * 4 + w) * 32;              // 32 queries per wave
    const unsigned short* Q = qb + (size_t)hi * NT * HD;
    const unsigned short* K = kb + (size_t)hi * NT * HD;
    const unsigned short* V = vt + (size_t)hi * HD * NT;

    const shortx8 qfA = *(const shortx8*)(Q + (size_t)(q0 + l16) * HD + quad * 8);
    const shortx8 qfB = *(const shortx8*)(Q + (size_t)(q0 + 16 + l16) * HD + quad * 8);
    // permuted K-row index: A row m holds key (m>>2)*8 + (m&3)  (g0) / +4 (g1)
    const int krow = (l16 >> 2) * 8 + (l16 & 3);
    // this wave's staging source (fragment w), per-lane 16B gather:
    const unsigned short* gsrc0;
    if (w == 0)      gsrc0 = K + (size_t)krow * HD + quad * 8;
    else if (w == 1) gsrc0 = K + (size_t)(krow + 4) * HD + quad * 8;
    else if (w == 2) gsrc0 = V + (size_t)l16 * NT + quad * 8;
    else             gsrc0 = V + (size_t)(16 + l16) * NT + quad * 8;
    const int gstep = (w < 2) ? 32 * HD : 32;            // elems per 32-key tile

    const shortx8 ones = {16256, 16256, 16256, 16256, 16256, 16256, 16256, 16256}; // bf16 1.0
    floatx4 oloA = {}, ohiA = {}, dsA = {};
    floatx4 oloB = {}, ohiB = {}, dsB = {};
    const floatx4 zero = {};

    GLD_LDS(gsrc0, &frag[0][w][0]);                      // stage tile 0
    __syncthreads();

    for (int t = 0; t < 32; t++) {
        if (t < 31) GLD_LDS(gsrc0 + (size_t)(t + 1) * gstep, &frag[(t + 1) & 1][w][0]);
        const unsigned short* fb = &frag[t & 1][0][0];
        const shortx8 kf0 = *(const shortx8*)(fb + 0 * 512 + lane * 8);
        const shortx8 kf1 = *(const shortx8*)(fb + 1 * 512 + lane * 8);
        const shortx8 vlo = *(const shortx8*)(fb + 2 * 512 + lane * 8);
        const shortx8 vhi = *(const shortx8*)(fb + 3 * 512 + lane * 8);
        const floatx4 sA0 = __builtin_amdgcn_mfma_f32_16x16x32_bf16(kf0, qfA, zero, 0, 0, 0);
        const floatx4 sA1 = __builtin_amdgcn_mfma_f32_16x16x32_bf16(kf1, qfA, zero, 0, 0, 0);
        const floatx4 sB0 = __builtin_amdgcn_mfma_f32_16x16x32_bf16(kf0, qfB, zero, 0, 0, 0);
        const floatx4 sB1 = __builtin_amdgcn_mfma_f32_16x16x32_bf16(kf1, qfB, zero, 0, 0, 0);
        float eA[8], eB[8];
#pragma unroll
        for (int r = 0; r < 4; r++) {
            eA[r]     = __builtin_amdgcn_exp2f(fmaf(sA0[r], C2, -M2));
            eA[4 + r] = __builtin_amdgcn_exp2f(fmaf(sA1[r], C2, -M2));
            eB[r]     = __builtin_amdgcn_exp2f(fmaf(sB0[r], C2, -M2));
            eB[4 + r] = __builtin_amdgcn_exp2f(fmaf(sB1[r], C2, -M2));
        }
        union { shortx8 s8; __hip_bfloat162 h[4]; } pA, pB;
#pragma unroll
        for (int i = 0; i < 4; i++) {
            pA.h[i] = __float22bfloat162_rn(make_float2(eA[2 * i], eA[2 * i + 1]));
            pB.h[i] = __float22bfloat162_rn(make_float2(eB[2 * i], eB[2 * i + 1]));
        }
        oloA = __builtin_amdgcn_mfma_f32_16x16x32_bf16(pA.s8, vlo, oloA, 0, 0, 0);
        ohiA = __builtin_amdgcn_mfma_f32_16x16x32_bf16(pA.s8, vhi, ohiA, 0, 0, 0);
        dsA  = __builtin_amdgcn_mfma_f32_16x16x32_bf16(pA.s8, ones, dsA, 0, 0, 0);
        oloB = __builtin_amdgcn_mfma_f32_16x16x32_bf16(pB.s8, vlo, oloB, 0, 0, 0);
        ohiB = __builtin_amdgcn_mfma_f32_16x16x32_bf16(pB.s8, vhi, ohiB, 0, 0, 0);
        dsB  = __builtin_amdgcn_mfma_f32_16x16x32_bf16(pB.s8, ones, dsB, 0, 0, 0);
        __syncthreads();   // staged tile t+1 landed; all waves done with buf t&1
    }
    // epilogue: write in A-fragment order (k = channel = h*32 + col)
    const int bi = hi / NH, h = hi % NH;
    const size_t mt0 = (size_t)bi * 64 + (q0 >> 4);      // mtile of tile A
    const int kqlo = l16 >> 3, kr = l16 & 7;
    unsigned short* pAp = aoutf + (mt0 * 12 + h) * 512 + kr;
    unsigned short* pBp = aoutf + ((mt0 + 1) * 12 + h) * 512 + kr;
#pragma unroll
    for (int r = 0; r < 4; r++) {
        const int mrow8 = (quad * 4 + r) * 8;
        const float invA = 1.0f / dsA[r], invB = 1.0f / dsB[r];
        pAp[kqlo * 128 + mrow8]       = f2bf(oloA[r] * invA);
        pAp[(2 + kqlo) * 128 + mrow8] = f2bf(ohiA[r] * invA);
        pBp[kqlo * 128 + mrow8]       = f2bf(oloB[r] * invB);
        pBp[(2 + kqlo) * 128 + mrow8] = f2bf(ohiB[r] * invB);
    }
}

// ---------------------------------------------------------------------------
// Proj GEMM from fragment-ordered operands + fp32 bias, fp32 (B, C, N) output.
__global__ __launch_bounds__(256) void k_proj(const unsigned short* __restrict__ aoutf,
                                              const unsigned short* __restrict__ wpf,
                                              const float* __restrict__ bias,
                                              float* __restrict__ out) {
    const int lane = threadIdx.x & 63, w = threadIdx.x >> 6;
    const int quad = lane >> 4, l16 = lane & 15;
    const int m0 = blockIdx.x * 128 + (w & 1) * 64;
    const int n0 = blockIdx.y * 128 + (w >> 1) * 64;
    floatx4 acc[4][4] = {};
    const unsigned short* abase = aoutf + ((size_t)(m0 >> 4) * 12 * 4 + quad) * 128 + l16 * 8;
    const unsigned short* bbase = wpf + ((size_t)(n0 >> 4) * 12 * 4 + quad) * 128 + l16 * 8;
    shortx8 a[4], b[4], a2[4], b2[4];
#pragma unroll
    for (int s = 0; s < 4; s++) {
        a[s] = *(const shortx8*)(abase + s * 6144);
        b[s] = *(const shortx8*)(bbase + s * 6144);
    }
    for (int ks = 0; ks < 12; ks++) {
        if (ks < 11) {
#pragma unroll
            for (int s = 0; s < 4; s++) {
                a2[s] = *(const shortx8*)(abase + s * 6144 + (ks + 1) * 512);
                b2[s] = *(const shortx8*)(bbase + s * 6144 + (ks + 1) * 512);
            }
        }
#pragma unroll
        for (int sm = 0; sm < 4; sm++)
#pragma unroll
            for (int sn = 0; sn < 4; sn++)
                acc[sm][sn] = __builtin_amdgcn_mfma_f32_16x16x32_bf16(a[sm], b[sn], acc[sm][sn], 0, 0, 0);
#pragma unroll
        for (int s = 0; s < 4; s++) { a[s] = a2[s]; b[s] = b2[s]; }
    }
    const int bi = m0 >> 10;
#pragma unroll
    for (int sn = 0; sn < 4; sn++) {
        const int o = n0 + sn * 16 + l16;
        const float bv = bias[o];
        float* orow = out + ((size_t)bi * DIM + o) * NT;
#pragma unroll
        for (int sm = 0; sm < 4; sm++) {
            const int nb = (m0 + sm * 16 + quad * 4) & 1023;
            float4 pack;
            pack.x = acc[sm][sn][0] + bv;
            pack.y = acc[sm][sn][1] + bv;
            pack.z = acc[sm][sn][2] + bv;
            pack.w = acc[sm][sn][3] + bv;
            *(float4*)(orow + nb) = pack;
        }
    }
}

// ---------------------------------------------------------------------------
extern "C" void kernel_launch(void* const* d_in, const int* in_sizes, int n_in,
                              void* d_out, int out_size, void* d_ws, size_t ws_size,
                              hipStream_t stream) {
    const float* x     = (const float*)d_in[0];
    const float* wqkv  = (const float*)d_in[1];
    const float* wproj = (const float*)d_in[2];
    const float* bias  = (const float*)d_in[3];
    float* out = (float*)d_out;

    // ws layout (bf16 elems): xtf | q | k | vT | wqf | wpf ; aoutf reuses xtf.
    unsigned short* xtf  = (unsigned short*)d_ws;
    unsigned short* qb   = xtf + 3145728;
    unsigned short* kb   = qb + 3145728;
    unsigned short* vt   = kb + 3145728;
    unsigned short* wqf  = vt + 3145728;
    unsigned short* wpf  = wqf + 442368;
    unsigned short* aoutf = xtf;                  // xtf dead after k_qkv

    k_pre<<<3648, 256, 0, stream>>>(x, wqkv, wproj, xtf, wqf, wpf);
    k_qkv<<<dim3(64, 9), 256, 0, stream>>>(xtf, wqf, qb, kb, vt);
    k_attn<<<768, 256, 0, stream>>>(qb, kb, vt, aoutf);
    k_proj<<<dim3(64, 3), 256, 0, stream>>>(aoutf, wpf, bias, out);
}